// Round 15
// baseline (148.122 us; speedup 1.0000x reference)
//
#include <hip/hip_runtime.h>

#define LQ 1024
#define CS 768
#define CZ 64
#define NH 12
#define HD 64

typedef float4 f4;
using bf16x8 = __attribute__((ext_vector_type(8))) short;
using f32x4  = __attribute__((ext_vector_type(4))) float;

static __device__ __forceinline__ unsigned short f2bf(float f) {
  unsigned int u = __float_as_uint(f);
  u += 0x7fffu + ((u >> 16) & 1u);
  return (unsigned short)(u >> 16);
}
static __device__ __forceinline__ float bf2f(unsigned short b) {
  return __uint_as_float(((unsigned int)b) << 16);
}
// packed f32x2 -> bf16x2 (RNE) in one instruction [gfx950]
static __device__ __forceinline__ unsigned cvtpk(float lo, float hi) {
  unsigned r;
  asm("v_cvt_pk_bf16_f32 %0, %1, %2" : "=v"(r) : "v"(lo), "v"(hi));
  return r;
}

// ============ kernel 1: ln_single + weight convert/transpose (fused) ============
__global__ __launch_bounds__(256) void ln_wconv_k(
    const float* __restrict__ x, const float* __restrict__ g,
    const float* __restrict__ b, unsigned short* __restrict__ s_out,
    const float* __restrict__ Wq, const float* __restrict__ Wk,
    const float* __restrict__ Wv, const float* __restrict__ Wg,
    const float* __restrict__ Wo, unsigned short* __restrict__ wt) {
  const int bid = blockIdx.x;
  const int t = threadIdx.x;
  if (bid < LQ) {
    const int row = bid;
    const float* xr = x + (size_t)row * CS;
    float v0 = xr[t], v1 = xr[t + 256], v2 = xr[t + 512];
    float s1 = v0 + v1 + v2;
    float s2 = v0 * v0 + v1 * v1 + v2 * v2;
#pragma unroll
    for (int m = 1; m < 64; m <<= 1) {
      s1 += __shfl_xor(s1, m);
      s2 += __shfl_xor(s2, m);
    }
    __shared__ float r1[4], r2[4];
    const int wid = t >> 6;
    if ((t & 63) == 0) { r1[wid] = s1; r2[wid] = s2; }
    __syncthreads();
    s1 = r1[0] + r1[1] + r1[2] + r1[3];
    s2 = r2[0] + r2[1] + r2[2] + r2[3];
    const float mu = s1 * (1.f / CS);
    const float var = s2 * (1.f / CS) - mu * mu;
    const float rs = rsqrtf(var + 1e-5f);
    s_out[(size_t)row * CS + t]       = f2bf((v0 - mu) * rs * g[t]       + b[t]);
    s_out[(size_t)row * CS + t + 256] = f2bf((v1 - mu) * rs * g[t + 256] + b[t + 256]);
    s_out[(size_t)row * CS + t + 512] = f2bf((v2 - mu) * rs * g[t + 512] + b[t + 512]);
  } else {
    int r = bid - LQ;                    // 0..719
    const int bz = r / 144; r %= 144;
    const int n0 = (r % 12) * 64, k0 = (r / 12) * 64;
    const float* W;
    switch (bz) {
      case 0: W = Wq; break;
      case 1: W = Wk; break;
      case 2: W = Wv; break;
      case 3: W = Wg; break;
      default: W = Wo; break;
    }
    unsigned short* o = wt + (size_t)bz * CS * CS;
    __shared__ float T[64][68];
    {
      const int rr = t >> 4, c = (t & 15) * 4;
#pragma unroll
      for (int u = 0; u < 4; ++u) {
        const f4 v = *(const f4*)&W[(size_t)(k0 + rr + u * 16) * CS + n0 + c];
        *(f4*)&T[rr + u * 16][c] = v;
      }
    }
    __syncthreads();
    {
      const int rn = t >> 2, ck = (t & 3) * 16;
      __align__(16) unsigned short tmp[16];
#pragma unroll
      for (int u = 0; u < 16; ++u) tmp[u] = f2bf(T[ck + u][rn]);
      unsigned short* dst = &o[(size_t)(n0 + rn) * CS + k0 + ck];
      *(uint4*)dst = ((const uint4*)tmp)[0];
      *(uint4*)(dst + 8) = ((const uint4*)tmp)[1];
    }
  }
}

// ============ kernel 2: pair-bias (4096 blocks, coalesced load+store) || QKVG GEMM (384) ============
// Pair path: R11's coalesced 1KB-per-instruction staging loads + swizzled zs +
// folded-LN MFMA, combined with R12's LDS-staged full-line bias writeout.
// biasF layout (attn-fragment), element (h, i, j):
//   flat = (((h*64 + (i>>4))*16 + (j>>6))*4 + ((j>>4)&3))*256
//          + ((i>>2)&3)*64 + (j&15)*4 + (i&3)
__global__ __launch_bounds__(256) void qkvg_pair_k(
    const unsigned short* __restrict__ s, const unsigned short* __restrict__ wt,
    const float* __restrict__ bg,
    unsigned short* __restrict__ qb, unsigned short* __restrict__ kb,
    unsigned short* __restrict__ vt, float* __restrict__ gpre,
    const float* __restrict__ pair, const float* __restrict__ zg,
    const float* __restrict__ zb, const float* __restrict__ Wb,
    unsigned short* __restrict__ biasF) {
  // union buffer: GEMM needs 33792 B; pair needs 32768(zs) + 6336(outT) + 2048(stats) = 41152 B
  __shared__ __align__(16) unsigned char smraw[41152];
  const int t = threadIdx.x;
  const int w = t >> 6, lane = t & 63, g = lane >> 4, c = lane & 15;

  if (blockIdx.x < 4096) {
    // ---- pair-bias path: coalesced staged loads -> zs -> stats -> MFMA -> outT -> bulk store ----
    unsigned short* zs = (unsigned short*)smraw;                 // 256 rows x 64 bf16, swizzled
    unsigned short* outT = (unsigned short*)(smraw + 32768);     // 12 heads x 264 (256 used)
    float* rstats = (float*)(smraw + 39104);                     // 256
    float* mstats = (float*)(smraw + 40128);                     // 256
    const int bid = blockIdx.x;
    const int i0 = (bid >> 4) * 4;
    const int j0 = (bid & 15) * 64;

    // stage: wave w loads row i0+w (16 KB) with 16 x 1KB-contiguous instructions
    const f32x4* src = (const f32x4*)(pair + ((size_t)(i0 + w) * LQ + j0) * CZ);
    f32x4 vv[16];
#pragma unroll
    for (int u = 0; u < 16; ++u) vv[u] = src[u * 64 + lane];

    // per-lane constants while loads are in flight
    const int csafe = (c < NH) ? c : 0;
    float C1 = 0.f, C2 = 0.f;
    for (int ch = 0; ch < CZ; ++ch) {
      const float wv = (c < NH) ? Wb[ch * NH + csafe] : 0.f;
      C1 = fmaf(zg[ch], wv, C1);
      C2 = fmaf(zb[ch], wv, C2);
    }
    bf16x8 wf0, wf1;
#pragma unroll
    for (int u = 0; u < 8; ++u) {
      const float w0 = (c < NH) ? zg[g * 8 + u] * Wb[(g * 8 + u) * NH + csafe] : 0.f;
      const float w1 = (c < NH) ? zg[32 + g * 8 + u] * Wb[(32 + g * 8 + u) * NH + csafe] : 0.f;
      wf0[u] = (short)f2bf(w0);
      wf1[u] = (short)f2bf(w1);
    }

    // convert + swizzled LDS write
#pragma unroll
    for (int u = 0; u < 16; ++u) {
      const int idx = u * 64 + lane;
      const int j = idx >> 4;            // row-local j (0..63)
      const int kq = idx & 15;           // 4-channel quarter index
      const int row = w * 64 + j;
      const int chunk = kq >> 1, half = kq & 1;
      uint2 pk;
      pk.x = cvtpk(vv[u][0], vv[u][1]);
      pk.y = cvtpk(vv[u][2], vv[u][3]);
      *(uint2*)&zs[row * 64 + ((chunk ^ (row & 7)) << 3) + (half << 2)] = pk;
    }
    __syncthreads();

    // stats: thread t <-> pair row t
    {
      float s1 = 0.f, s2 = 0.f;
      const int r7 = t & 7;
#pragma unroll
      for (int k = 0; k < 8; ++k) {
        const uint4 q = *(const uint4*)&zs[t * 64 + ((k ^ r7) << 3)];
        const float f0 = __uint_as_float(q.x << 16), f1 = __uint_as_float(q.x & 0xffff0000u);
        const float f2 = __uint_as_float(q.y << 16), f3 = __uint_as_float(q.y & 0xffff0000u);
        const float f4v = __uint_as_float(q.z << 16), f5 = __uint_as_float(q.z & 0xffff0000u);
        const float f6 = __uint_as_float(q.w << 16), f7 = __uint_as_float(q.w & 0xffff0000u);
        s1 += ((f0 + f1) + (f2 + f3)) + ((f4v + f5) + (f6 + f7));
        s2 += ((f0 * f0 + f1 * f1) + (f2 * f2 + f3 * f3))
            + ((f4v * f4v + f5 * f5) + (f6 * f6 + f7 * f7));
      }
      const float mu = s1 * (1.f / CZ);
      const float var = s2 * (1.f / CZ) - mu * mu;
      const float rs = rsqrtf(var + 1e-5f);
      rstats[t] = rs;
      mstats[t] = -rs * mu;
    }
    __syncthreads();

    // MFMA: wave w handles j-window w*16..w*16+15, 4 groups of 4 j; results to outT
    const int il = c & 3, jl = c >> 2;
#pragma unroll
    for (int mm = 0; mm < 4; ++mm) {
      const int jloc = w * 16 + mm * 4;
      const int arow = il * 64 + jloc + jl;      // A-row (lane c) = pair (il, jloc+jl)
      const int r7a = arow & 7;
      const bf16x8 a0 = *(const bf16x8*)&zs[arow * 64 + ((g ^ r7a) << 3)];
      const bf16x8 a1 = *(const bf16x8*)&zs[arow * 64 + (((4 + g) ^ r7a) << 3)];
      f32x4 dd = (f32x4){0.f, 0.f, 0.f, 0.f};
      dd = __builtin_amdgcn_mfma_f32_16x16x32_bf16(a0, wf0, dd, 0, 0, 0);
      dd = __builtin_amdgcn_mfma_f32_16x16x32_bf16(a1, wf1, dd, 0, 0, 0);

      const int jg = jloc + g;                   // D rows g*4+r = pair (r, jg)
      const float rs0 = rstats[jg],       mp0 = mstats[jg];
      const float rs1 = rstats[64 + jg],  mp1 = mstats[64 + jg];
      const float rs2 = rstats[128 + jg], mp2 = mstats[128 + jg];
      const float rs3 = rstats[192 + jg], mp3 = mstats[192 + jg];
      if (c < NH) {
        const float b0 = fmaf(rs0, dd[0], fmaf(mp0, C1, C2));
        const float b1 = fmaf(rs1, dd[1], fmaf(mp1, C1, C2));
        const float b2 = fmaf(rs2, dd[2], fmaf(mp2, C1, C2));
        const float b3 = fmaf(rs3, dd[3], fmaf(mp3, C1, C2));
        // outT: head c, nb strip = jg>>4 (= w), col = jg&15, rows r packed x4
        uint2 st;
        st.x = cvtpk(b0, b1);
        st.y = cvtpk(b2, b3);
        *(uint2*)&outT[c * 264 + (jg >> 4) * 64 + (jg & 15) * 4] = st;
      }
    }
    __syncthreads();

    // bulk coalesced writeout: 12 heads x 4 nb x 128 B (full lines)
    const int gi = i0 >> 4, ga = (i0 >> 2) & 3;
    const int jt0 = j0 >> 6;
#pragma unroll
    for (int rep = 0; rep < 2; ++rep) {
      const int idx = rep * 256 + t;            // 0..511, active < 384
      if (idx < 384) {
        const int hh = idx >> 5;                // head 0..11
        const int sp = (idx >> 3) & 3;          // nb strip 0..3
        const int sub = idx & 7;                // 16-B granule
        const uint4 v = *(const uint4*)&outT[hh * 264 + sp * 64 + sub * 8];
        const size_t flat = ((((size_t)hh * 64 + gi) * 16 + jt0) * 4 + sp) * 256
                          + (size_t)ga * 64 + sub * 8;
        *(uint4*)&biasF[flat] = v;
      }
    }
  } else {
    // ---- QKVG GEMM path: 64x128 tile, BK=64, 2x4 acc (R13 verbatim) ----
    unsigned short (*As)[88] = (unsigned short (*)[88])smraw;
    unsigned short (*Bs)[88] = (unsigned short (*)[88])(smraw + 64 * 88 * 2);
    const int gb = blockIdx.x - 4096;
    const int wm = w >> 1, wn = w & 1;
    const int bx = gb % 24, by = gb / 24;
    const int m0 = by * 64;
    const int wid = bx / 6;
    const int nl0 = (bx % 6) * 128;
    const unsigned short* B = wt + (size_t)wid * CS * CS;

    f32x4 acc[2][4];
#pragma unroll
    for (int i = 0; i < 2; ++i)
#pragma unroll
      for (int j = 0; j < 4; ++j) acc[i][j] = (f32x4){0.f, 0.f, 0.f, 0.f};

    const int sra = t >> 2, sha = (t & 3) * 16;
    const int srb = t >> 1, shb = (t & 1) * 32;
    for (int kt = 0; kt < CS; kt += 64) {
      __syncthreads();
#pragma unroll
      for (int u = 0; u < 2; ++u)
        *(uint4*)&As[sra][sha + u * 8] = *(const uint4*)&s[(size_t)(m0 + sra) * CS + kt + sha + u * 8];
#pragma unroll
      for (int u = 0; u < 4; ++u)
        *(uint4*)&Bs[srb][shb + u * 8] = *(const uint4*)&B[(size_t)(nl0 + srb) * CS + kt + shb + u * 8];
      __syncthreads();
#pragma unroll
      for (int kk = 0; kk < 64; kk += 32) {
        bf16x8 af[2], bfr[4];
#pragma unroll
        for (int i = 0; i < 2; ++i) af[i] = *(const bf16x8*)&As[wm * 32 + i * 16 + c][kk + g * 8];
#pragma unroll
        for (int j = 0; j < 4; ++j) bfr[j] = *(const bf16x8*)&Bs[wn * 64 + j * 16 + c][kk + g * 8];
#pragma unroll
        for (int i = 0; i < 2; ++i)
#pragma unroll
          for (int j = 0; j < 4; ++j)
            acc[i][j] = __builtin_amdgcn_mfma_f32_16x16x32_bf16(af[i], bfr[j], acc[i][j], 0, 0, 0);
      }
    }
#pragma unroll
    for (int i = 0; i < 2; ++i) {
#pragma unroll
      for (int j = 0; j < 4; ++j) {
        const int mb = m0 + wm * 32 + i * 16 + g * 4;
        const int nn = nl0 + wn * 64 + j * 16 + c;
        const f32x4 a = acc[i][j];
        if (wid == 0) {
#pragma unroll
          for (int r = 0; r < 4; ++r) qb[(size_t)(mb + r) * CS + nn] = f2bf(a[r] * 0.125f);
        } else if (wid == 1) {
#pragma unroll
          for (int r = 0; r < 4; ++r) kb[(size_t)(mb + r) * CS + nn] = f2bf(a[r]);
        } else if (wid == 2) {
          ushort4 pk;
          pk.x = f2bf(a[0]); pk.y = f2bf(a[1]); pk.z = f2bf(a[2]); pk.w = f2bf(a[3]);
          *(ushort4*)&vt[(size_t)nn * LQ + mb] = pk;
        } else {
          const float bb = bg[nn];
#pragma unroll
          for (int r = 0; r < 4; ++r) gpre[(size_t)(mb + r) * CS + nn] = a[r] + bb;
        }
      }
    }
  }
}

// ============ kernel 3: MFMA flash attention, j-split x2, double-buffered ============
__global__ __launch_bounds__(256) void attn_k(
    const unsigned short* __restrict__ q, const unsigned short* __restrict__ k,
    const unsigned short* __restrict__ vt, const unsigned short* __restrict__ biasF,
    float* __restrict__ Opart, float* __restrict__ ml) {
  __shared__ __align__(16) unsigned short Qs[64][88];
  __shared__ __align__(16) unsigned short Ks[2][64][88];
  __shared__ __align__(16) unsigned short Vts[2][64][88];
  __shared__ __align__(16) unsigned short Ps[4][16][88];
  const int bx = blockIdx.x, h = blockIdx.y, z = blockIdx.z;
  const int i0 = bx * 64;
  const int jb = z * 512;
  const int t = threadIdx.x;
  const int w = t >> 6, lane = t & 63, g = lane >> 4, c = lane & 15;
  const int sr = t >> 2, sc = (t & 3) * 16;

#pragma unroll
  for (int u = 0; u < 2; ++u) {
    *(uint4*)&Qs[sr][sc + u * 8]     = *(const uint4*)&q[(size_t)(i0 + sr) * CS + h * HD + sc + u * 8];
    *(uint4*)&Ks[0][sr][sc + u * 8]  = *(const uint4*)&k[(size_t)(jb + sr) * CS + h * HD + sc + u * 8];
    *(uint4*)&Vts[0][sr][sc + u * 8] = *(const uint4*)&vt[(size_t)(h * HD + sr) * LQ + jb + sc + u * 8];
  }
  const size_t bbase = ((((size_t)h * 64 + (bx * 4 + w)) * 16 + (size_t)z * 8) * 4) * 256 + lane * 4;
  ushort4 bcur[4];
#pragma unroll
  for (int nb = 0; nb < 4; ++nb) bcur[nb] = *(const ushort4*)&biasF[bbase + nb * 256];
  __syncthreads();

  const bf16x8 aq0 = *(const bf16x8*)&Qs[w * 16 + c][g * 8];
  const bf16x8 aq1 = *(const bf16x8*)&Qs[w * 16 + c][32 + g * 8];

  f32x4 acc_o[4];
#pragma unroll
  for (int nb = 0; nb < 4; ++nb) acc_o[nb] = (f32x4){0.f, 0.f, 0.f, 0.f};
  float m_run[4] = {-1e30f, -1e30f, -1e30f, -1e30f};
  float l_run[4] = {0.f, 0.f, 0.f, 0.f};

  for (int jt = 0; jt < 8; ++jt) {
    const int cur = jt & 1;
    uint4 kr0, kr1, vr0, vr1;
    ushort4 bnx[4];
    if (jt < 7) {
      const int jn = jb + (jt + 1) * 64;
      kr0 = *(const uint4*)&k[(size_t)(jn + sr) * CS + h * HD + sc];
      kr1 = *(const uint4*)&k[(size_t)(jn + sr) * CS + h * HD + sc + 8];
      vr0 = *(const uint4*)&vt[(size_t)(h * HD + sr) * LQ + jn + sc];
      vr1 = *(const uint4*)&vt[(size_t)(h * HD + sr) * LQ + jn + sc + 8];
#pragma unroll
      for (int nb = 0; nb < 4; ++nb)
        bnx[nb] = *(const ushort4*)&biasF[bbase + (size_t)(jt + 1) * 1024 + nb * 256];
    }

    f32x4 sa[4];
#pragma unroll
    for (int nb = 0; nb < 4; ++nb) {
      f32x4 ci;
      ci[0] = bf2f(bcur[nb].x); ci[1] = bf2f(bcur[nb].y);
      ci[2] = bf2f(bcur[nb].z); ci[3] = bf2f(bcur[nb].w);
      const bf16x8 b0 = *(const bf16x8*)&Ks[cur][nb * 16 + c][g * 8];
      const bf16x8 b1 = *(const bf16x8*)&Ks[cur][nb * 16 + c][32 + g * 8];
      ci = __builtin_amdgcn_mfma_f32_16x16x32_bf16(aq0, b0, ci, 0, 0, 0);
      ci = __builtin_amdgcn_mfma_f32_16x16x32_bf16(aq1, b1, ci, 0, 0, 0);
      sa[nb] = ci;
    }

    float mt[4];
#pragma unroll
    for (int r = 0; r < 4; ++r) {
      float v = fmaxf(fmaxf(sa[0][r], sa[1][r]), fmaxf(sa[2][r], sa[3][r]));
      v = fmaxf(v, __shfl_xor(v, 1));
      v = fmaxf(v, __shfl_xor(v, 2));
      v = fmaxf(v, __shfl_xor(v, 4));
      v = fmaxf(v, __shfl_xor(v, 8));
      mt[r] = v;
    }
    float scale[4], ps[4];
#pragma unroll
    for (int r = 0; r < 4; ++r) {
      const float mn = fmaxf(m_run[r], mt[r]);
      scale[r] = __expf(m_run[r] - mn);
      m_run[r] = mn;
      ps[r] = 0.f;
    }
#pragma unroll
    for (int nb = 0; nb < 4; ++nb) {
#pragma unroll
      for (int r = 0; r < 4; ++r) {
        const float p = __expf(sa[nb][r] - m_run[r]);
        ps[r] += p;
        Ps[w][g * 4 + r][nb * 16 + c] = f2bf(p);
      }
    }
#pragma unroll
    for (int r = 0; r < 4; ++r) {
      float v = ps[r];
      v += __shfl_xor(v, 1);
      v += __shfl_xor(v, 2);
      v += __shfl_xor(v, 4);
      v += __shfl_xor(v, 8);
      l_run[r] = l_run[r] * scale[r] + v;
#pragma unroll
      for (int nb = 0; nb < 4; ++nb) acc_o[nb][r] *= scale[r];
    }

#pragma unroll
    for (int kb = 0; kb < 2; ++kb) {
      const bf16x8 pa = *(const bf16x8*)&Ps[w][c][kb * 32 + g * 8];
#pragma unroll
      for (int nb = 0; nb < 4; ++nb) {
        const bf16x8 bv = *(const bf16x8*)&Vts[cur][nb * 16 + c][kb * 32 + g * 8];
        acc_o[nb] = __builtin_amdgcn_mfma_f32_16x16x32_bf16(pa, bv, acc_o[nb], 0, 0, 0);
      }
    }

    if (jt < 7) {
      *(uint4*)&Ks[cur ^ 1][sr][sc]      = kr0;
      *(uint4*)&Ks[cur ^ 1][sr][sc + 8]  = kr1;
      *(uint4*)&Vts[cur ^ 1][sr][sc]     = vr0;
      *(uint4*)&Vts[cur ^ 1][sr][sc + 8] = vr1;
      __syncthreads();
#pragma unroll
      for (int nb = 0; nb < 4; ++nb) bcur[nb] = bnx[nb];
    }
  }

  const size_t rowb = (size_t)(z * NH + h) * LQ + i0 + w * 16 + g * 4;
#pragma unroll
  for (int nb = 0; nb < 4; ++nb)
#pragma unroll
    for (int r = 0; r < 4; ++r)
      Opart[(rowb + r) * HD + nb * 16 + c] = acc_o[nb][r];
  if (c == 0) {
#pragma unroll
    for (int r = 0; r < 4; ++r) {
      ml[(rowb + r) * 2]     = m_run[r];
      ml[(rowb + r) * 2 + 1] = l_run[r];
    }
  }
}

// ============ kernel 4: combine the two j-halves ============
__global__ __launch_bounds__(256) void combine_k(
    const float* __restrict__ Opart, const float* __restrict__ ml,
    unsigned short* __restrict__ attno) {
  const int t = threadIdx.x;
  const int row = blockIdx.x * 4 + (t >> 6);
  const int d = t & 63;
  const int h = row >> 10, i = row & 1023;
  const size_t r0 = (size_t)h * LQ + i;
  const size_t r1 = (size_t)(NH + h) * LQ + i;
  const float m0 = ml[r0 * 2], l0 = ml[r0 * 2 + 1];
  const float m1 = ml[r1 * 2], l1 = ml[r1 * 2 + 1];
  const float M = fmaxf(m0, m1);
  const float a0 = __expf(m0 - M), a1 = __expf(m1 - M);
  const float L = a0 * l0 + a1 * l1;
  const float o = (a0 * Opart[r0 * HD + d] + a1 * Opart[r1 * HD + d]) / L;
  attno[(size_t)i * CS + h * HD + d] = f2bf(o);
}

// ============ kernel 5: final GEMM (64x128 tiles) + gated residual ============
__global__ __launch_bounds__(256) void gemm_final_k(
    const unsigned short* __restrict__ A, const unsigned short* __restrict__ wt,
    const float* __restrict__ bout, const float* __restrict__ single,
    const float* __restrict__ gpre, float* __restrict__ out) {
  __shared__ __align__(16) unsigned short As[64][88];
  __shared__ __align__(16) unsigned short Bs[128][88];
  const int t = threadIdx.x;
  const int wave = t >> 6, lane = t & 63, g = lane >> 4, c = lane & 15;
  const int wm = wave >> 1, wn = wave & 1;
  const int m0 = blockIdx.y * 64;
  const int nl0 = blockIdx.x * 128;
  const unsigned short* B = wt + (size_t)4 * CS * CS;

  f32x4 acc[2][4];
#pragma unroll
  for (int i = 0; i < 2; ++i)
#pragma unroll
    for (int j = 0; j < 4; ++j) acc[i][j] = (f32x4){0.f, 0.f, 0.f, 0.f};

  const int sra = t >> 2, sha = (t & 3) * 16;
  const int srb = t >> 1, shb = (t & 1) * 32;
  for (int kt = 0; kt < CS; kt += 64) {
    __syncthreads();
#pragma unroll
    for (int u = 0; u < 2; ++u)
      *(uint4*)&As[sra][sha + u * 8] = *(const uint4*)&A[(size_t)(m0 + sra) * CS + kt + sha + u * 8];
#pragma unroll
    for (int u = 0; u < 4; ++u)
      *(uint4*)&Bs[srb][shb + u * 8] = *(const uint4*)&B[(size_t)(nl0 + srb) * CS + kt + shb + u * 8];
    __syncthreads();
#pragma unroll
    for (int kk = 0; kk < 64; kk += 32) {
      bf16x8 af[2], bfr[4];
#pragma unroll
      for (int i = 0; i < 2; ++i) af[i] = *(const bf16x8*)&As[wm * 32 + i * 16 + c][kk + g * 8];
#pragma unroll
      for (int j = 0; j < 4; ++j) bfr[j] = *(const bf16x8*)&Bs[wn * 64 + j * 16 + c][kk + g * 8];
#pragma unroll
      for (int i = 0; i < 2; ++i)
#pragma unroll
        for (int j = 0; j < 4; ++j)
          acc[i][j] = __builtin_amdgcn_mfma_f32_16x16x32_bf16(af[i], bfr[j], acc[i][j], 0, 0, 0);
    }
  }

#pragma unroll
  for (int i = 0; i < 2; ++i) {
#pragma unroll
    for (int j = 0; j < 4; ++j) {
      const int mb = m0 + wm * 32 + i * 16 + g * 4;
      const int nn = nl0 + wn * 64 + j * 16 + c;
      const float bb = bout[nn];
      const f32x4 a = acc[i][j];
#pragma unroll
      for (int r = 0; r < 4; ++r) {
        const size_t idx = (size_t)(mb + r) * CS + nn;
        const float gate = 1.f / (1.f + __expf(-gpre[idx]));
        out[idx] = single[idx] + gate * (a[r] + bb);
      }
    }
  }
}

extern "C" void kernel_launch(void* const* d_in, const int* in_sizes, int n_in,
                              void* d_out, int out_size, void* d_ws, size_t ws_size,
                              hipStream_t stream) {
  const float* single = (const float*)d_in[0];
  const float* pair   = (const float*)d_in[1];
  const float* ln_s_g = (const float*)d_in[2];
  const float* ln_s_b = (const float*)d_in[3];
  const float* ln_z_g = (const float*)d_in[4];
  const float* ln_z_b = (const float*)d_in[5];
  const float* Wq     = (const float*)d_in[6];
  const float* Wk     = (const float*)d_in[7];
  const float* Wv     = (const float*)d_in[8];
  const float* Wb     = (const float*)d_in[9];
  const float* Wout   = (const float*)d_in[10];
  const float* bout   = (const float*)d_in[11];
  const float* Wgate  = (const float*)d_in[12];
  const float* bgate  = (const float*)d_in[13];
  float* out = (float*)d_out;

  unsigned short* s_bf  = (unsigned short*)d_ws;
  unsigned short* wt    = s_bf  + (size_t)LQ * CS;
  unsigned short* q_bf  = wt    + (size_t)5 * CS * CS;
  unsigned short* k_bf  = q_bf  + (size_t)LQ * CS;
  unsigned short* vt_bf = k_bf  + (size_t)LQ * CS;
  unsigned short* attno = vt_bf + (size_t)CS * LQ;
  unsigned short* biasF = attno + (size_t)LQ * CS;
  float* gpre  = (float*)(biasF + (size_t)NH * LQ * LQ);
  float* Opart = gpre  + (size_t)LQ * CS;
  float* mlw   = Opart + (size_t)2 * NH * LQ * HD;

  hipLaunchKernelGGL(ln_wconv_k, dim3(LQ + 720), dim3(256), 0, stream,
                     single, ln_s_g, ln_s_b, s_bf, Wq, Wk, Wv, Wgate, Wout, wt);
  hipLaunchKernelGGL(qkvg_pair_k, dim3(4096 + 384), dim3(256), 0, stream,
                     s_bf, wt, bgate, q_bf, k_bf, vt_bf, gpre,
                     pair, ln_z_g, ln_z_b, Wb, biasF);
  hipLaunchKernelGGL(attn_k, dim3(16, NH, 2), dim3(256), 0, stream,
                     q_bf, k_bf, vt_bf, biasF, Opart, mlw);
  hipLaunchKernelGGL(combine_k, dim3(3072), dim3(256), 0, stream,
                     Opart, mlw, attno);
  hipLaunchKernelGGL(gemm_final_k, dim3(6, 16), dim3(256), 0, stream,
                     attno, wt, bout, single, gpre, out);
}

// Round 16
// 119.781 us; speedup vs baseline: 1.2366x; 1.2366x over previous
//
#include <hip/hip_runtime.h>

#define LQ 1024
#define CS 768
#define CZ 64
#define NH 12
#define HD 64

typedef float4 f4;
using bf16x8 = __attribute__((ext_vector_type(8))) short;
using f32x4  = __attribute__((ext_vector_type(4))) float;

static __device__ __forceinline__ unsigned short f2bf(float f) {
  unsigned int u = __float_as_uint(f);
  u += 0x7fffu + ((u >> 16) & 1u);
  return (unsigned short)(u >> 16);
}
static __device__ __forceinline__ float bf2f(unsigned short b) {
  return __uint_as_float(((unsigned int)b) << 16);
}
// packed f32x2 -> bf16x2 (RNE) in one instruction [gfx950]
static __device__ __forceinline__ unsigned cvtpk(float lo, float hi) {
  unsigned r;
  asm("v_cvt_pk_bf16_f32 %0, %1, %2" : "=v"(r) : "v"(lo), "v"(hi));
  return r;
}

// ============ kernel 1: ln_single + weight convert/transpose (fused) ============
__global__ __launch_bounds__(256) void ln_wconv_k(
    const float* __restrict__ x, const float* __restrict__ g,
    const float* __restrict__ b, unsigned short* __restrict__ s_out,
    const float* __restrict__ Wq, const float* __restrict__ Wk,
    const float* __restrict__ Wv, const float* __restrict__ Wg,
    const float* __restrict__ Wo, unsigned short* __restrict__ wt) {
  const int bid = blockIdx.x;
  const int t = threadIdx.x;
  if (bid < LQ) {
    const int row = bid;
    const float* xr = x + (size_t)row * CS;
    float v0 = xr[t], v1 = xr[t + 256], v2 = xr[t + 512];
    float s1 = v0 + v1 + v2;
    float s2 = v0 * v0 + v1 * v1 + v2 * v2;
#pragma unroll
    for (int m = 1; m < 64; m <<= 1) {
      s1 += __shfl_xor(s1, m);
      s2 += __shfl_xor(s2, m);
    }
    __shared__ float r1[4], r2[4];
    const int wid = t >> 6;
    if ((t & 63) == 0) { r1[wid] = s1; r2[wid] = s2; }
    __syncthreads();
    s1 = r1[0] + r1[1] + r1[2] + r1[3];
    s2 = r2[0] + r2[1] + r2[2] + r2[3];
    const float mu = s1 * (1.f / CS);
    const float var = s2 * (1.f / CS) - mu * mu;
    const float rs = rsqrtf(var + 1e-5f);
    s_out[(size_t)row * CS + t]       = f2bf((v0 - mu) * rs * g[t]       + b[t]);
    s_out[(size_t)row * CS + t + 256] = f2bf((v1 - mu) * rs * g[t + 256] + b[t + 256]);
    s_out[(size_t)row * CS + t + 512] = f2bf((v2 - mu) * rs * g[t + 512] + b[t + 512]);
  } else {
    int r = bid - LQ;                    // 0..719
    const int bz = r / 144; r %= 144;
    const int n0 = (r % 12) * 64, k0 = (r / 12) * 64;
    const float* W;
    switch (bz) {
      case 0: W = Wq; break;
      case 1: W = Wk; break;
      case 2: W = Wv; break;
      case 3: W = Wg; break;
      default: W = Wo; break;
    }
    unsigned short* o = wt + (size_t)bz * CS * CS;
    __shared__ float T[64][68];
    {
      const int rr = t >> 4, c = (t & 15) * 4;
#pragma unroll
      for (int u = 0; u < 4; ++u) {
        const f4 v = *(const f4*)&W[(size_t)(k0 + rr + u * 16) * CS + n0 + c];
        *(f4*)&T[rr + u * 16][c] = v;
      }
    }
    __syncthreads();
    {
      const int rn = t >> 2, ck = (t & 3) * 16;
      __align__(16) unsigned short tmp[16];
#pragma unroll
      for (int u = 0; u < 16; ++u) tmp[u] = f2bf(T[ck + u][rn]);
      unsigned short* dst = &o[(size_t)(n0 + rn) * CS + k0 + ck];
      *(uint4*)dst = ((const uint4*)tmp)[0];
      *(uint4*)(dst + 8) = ((const uint4*)tmp)[1];
    }
  }
}

// ============ kernel 2: pair-bias (2048 blocks) || QKVG GEMM (384 blocks) fused ============
// Pair path: folded-LN MFMA with register prefetch + LDS-staged coalesced
// writeout (R12/R13 proven best). GEMM path: 64x128/BK=64. 33.8 KB LDS union.
// biasF layout (attn-fragment), element (h, i, j):
//   flat = (((h*64 + (i>>4))*16 + (j>>6))*4 + ((j>>4)&3))*256
//          + ((i>>2)&3)*64 + (j&15)*4 + (i&3)
__global__ __launch_bounds__(256) void qkvg_pair_k(
    const unsigned short* __restrict__ s, const unsigned short* __restrict__ wt,
    const float* __restrict__ bg,
    unsigned short* __restrict__ qb, unsigned short* __restrict__ kb,
    unsigned short* __restrict__ vt, float* __restrict__ gpre,
    const float* __restrict__ pair, const float* __restrict__ zg,
    const float* __restrict__ zb, const float* __restrict__ Wb,
    unsigned short* __restrict__ biasF) {
  __shared__ __align__(16) unsigned short sm[64 * 88 + 128 * 88];  // 33.8 KB union
  const int bid = blockIdx.x;
  const int t = threadIdx.x;
  const int w = t >> 6, lane = t & 63, g = lane >> 4, c = lane & 15;

  if (bid < 2048) {
    // ---- pair-bias path ----
    unsigned short* outT = sm;  // uses 12*520+8 = 6248 shorts
    const int i0 = (bid >> 3) * 4;
    const int j0 = (bid & 7) * 128;
    const int il = c & 3, jl = c >> 2;
    const int irow = i0 + il;
    const int g2 = g * 2;

    const int csafe = (c < NH) ? c : 0;
    float C1 = 0.f, C2 = 0.f;
    for (int ch = 0; ch < CZ; ++ch) {
      const float wv = (c < NH) ? Wb[ch * NH + csafe] : 0.f;
      C1 = fmaf(zg[ch], wv, C1);
      C2 = fmaf(zb[ch], wv, C2);
    }
    bf16x8 wf0, wf1;
#pragma unroll
    for (int u = 0; u < 8; ++u) {
      const float w0 = (c < NH) ? zg[g * 8 + u] * Wb[(g * 8 + u) * NH + csafe] : 0.f;
      const float w1 = (c < NH) ? zg[32 + g * 8 + u] * Wb[(32 + g * 8 + u) * NH + csafe] : 0.f;
      wf0[u] = (short)f2bf(w0);
      wf1[u] = (short)f2bf(w1);
    }

    f32x4 p00, p01, p02, p03;   // buffer A
    f32x4 p10, p11, p12, p13;   // buffer B
    {
      const f32x4* s0 = (const f32x4*)(pair + ((size_t)irow * LQ + (j0 + w * 32 + jl)) * CZ);
      p00 = s0[g2]; p01 = s0[g2 + 1]; p02 = s0[g2 + 8]; p03 = s0[g2 + 9];
    }
#pragma unroll
    for (int it = 0; it < 8; ++it) {
      const bool useA = (it & 1) == 0;
      if (it < 7) {
        const f32x4* sn = (const f32x4*)(pair + ((size_t)irow * LQ + (j0 + w * 32 + (it + 1) * 4 + jl)) * CZ);
        if (useA) { p10 = sn[g2]; p11 = sn[g2 + 1]; p12 = sn[g2 + 8]; p13 = sn[g2 + 9]; }
        else      { p00 = sn[g2]; p01 = sn[g2 + 1]; p02 = sn[g2 + 8]; p03 = sn[g2 + 9]; }
      }
      const f32x4 x0a = useA ? p00 : p10;
      const f32x4 x0b = useA ? p01 : p11;
      const f32x4 x1a = useA ? p02 : p12;
      const f32x4 x1b = useA ? p03 : p13;

      float s1 = (((x0a[0] + x0a[1]) + (x0a[2] + x0a[3])) + ((x0b[0] + x0b[1]) + (x0b[2] + x0b[3])))
               + (((x1a[0] + x1a[1]) + (x1a[2] + x1a[3])) + ((x1b[0] + x1b[1]) + (x1b[2] + x1b[3])));
      float s2 = (((x0a[0]*x0a[0] + x0a[1]*x0a[1]) + (x0a[2]*x0a[2] + x0a[3]*x0a[3]))
               +  ((x0b[0]*x0b[0] + x0b[1]*x0b[1]) + (x0b[2]*x0b[2] + x0b[3]*x0b[3])))
               + (((x1a[0]*x1a[0] + x1a[1]*x1a[1]) + (x1a[2]*x1a[2] + x1a[3]*x1a[3]))
               +  ((x1b[0]*x1b[0] + x1b[1]*x1b[1]) + (x1b[2]*x1b[2] + x1b[3]*x1b[3])));
      s1 += __shfl_xor(s1, 16); s1 += __shfl_xor(s1, 32);
      s2 += __shfl_xor(s2, 16); s2 += __shfl_xor(s2, 32);
      const float mu = s1 * (1.f / CZ);
      const float var = s2 * (1.f / CZ) - mu * mu;
      const float rs = rsqrtf(var + 1e-5f);
      const float mup = -rs * mu;

      union { unsigned u[4]; bf16x8 v8; } A, B;
      A.u[0] = cvtpk(x0a[0], x0a[1]); A.u[1] = cvtpk(x0a[2], x0a[3]);
      A.u[2] = cvtpk(x0b[0], x0b[1]); A.u[3] = cvtpk(x0b[2], x0b[3]);
      B.u[0] = cvtpk(x1a[0], x1a[1]); B.u[1] = cvtpk(x1a[2], x1a[3]);
      B.u[2] = cvtpk(x1b[0], x1b[1]); B.u[3] = cvtpk(x1b[2], x1b[3]);

      f32x4 dd = (f32x4){0.f, 0.f, 0.f, 0.f};
      dd = __builtin_amdgcn_mfma_f32_16x16x32_bf16(A.v8, wf0, dd, 0, 0, 0);
      dd = __builtin_amdgcn_mfma_f32_16x16x32_bf16(B.v8, wf1, dd, 0, 0, 0);

      const float rr0 = __shfl(rs, g * 4 + 0), mm0 = __shfl(mup, g * 4 + 0);
      const float rr1 = __shfl(rs, g * 4 + 1), mm1 = __shfl(mup, g * 4 + 1);
      const float rr2 = __shfl(rs, g * 4 + 2), mm2 = __shfl(mup, g * 4 + 2);
      const float rr3 = __shfl(rs, g * 4 + 3), mm3 = __shfl(mup, g * 4 + 3);

      if (c < NH) {
        const float b0 = fmaf(rr0, dd[0], fmaf(mm0, C1, C2));
        const float b1 = fmaf(rr1, dd[1], fmaf(mm1, C1, C2));
        const float b2 = fmaf(rr2, dd[2], fmaf(mm2, C1, C2));
        const float b3 = fmaf(rr3, dd[3], fmaf(mm3, C1, C2));
        const int jrel = w * 32 + it * 4 + g;
        const int sp = jrel >> 4;
        uint2 st;
        st.x = cvtpk(b0, b1);
        st.y = cvtpk(b2, b3);
        *(uint2*)&outT[c * 520 + sp * 64 + (jrel & 15) * 4] = st;
      }
    }
    __syncthreads();

    // bulk coalesced writeout: 12 heads x 8 strips x 128 B
    const int gi = i0 >> 4, ga = (i0 >> 2) & 3;
#pragma unroll
    for (int rep = 0; rep < 3; ++rep) {
      const int idx = rep * 256 + t;
      const int hh = idx >> 6;
      const int sp = (idx >> 3) & 7;
      const int sub = idx & 7;
      const uint4 v = *(const uint4*)&outT[hh * 520 + sp * 64 + sub * 8];
      const size_t flat = ((((size_t)hh * 64 + gi) * 16 + (j0 >> 6) + (sp >> 2)) * 4 + (sp & 3)) * 256
                        + (size_t)ga * 64 + sub * 8;
      *(uint4*)&biasF[flat] = v;
    }
  } else {
    // ---- QKVG GEMM path: 64x128 tile, BK=64, 2x4 acc ----
    unsigned short (*As)[88] = (unsigned short (*)[88])sm;
    unsigned short (*Bs)[88] = (unsigned short (*)[88])(sm + 64 * 88);
    const int gb = bid - 2048;
    const int wm = w >> 1, wn = w & 1;
    const int bx = gb % 24, by = gb / 24;
    const int m0 = by * 64;
    const int wid = bx / 6;
    const int nl0 = (bx % 6) * 128;
    const unsigned short* B = wt + (size_t)wid * CS * CS;

    f32x4 acc[2][4];
#pragma unroll
    for (int i = 0; i < 2; ++i)
#pragma unroll
      for (int j = 0; j < 4; ++j) acc[i][j] = (f32x4){0.f, 0.f, 0.f, 0.f};

    const int sra = t >> 2, sha = (t & 3) * 16;
    const int srb = t >> 1, shb = (t & 1) * 32;
    for (int kt = 0; kt < CS; kt += 64) {
      __syncthreads();
#pragma unroll
      for (int u = 0; u < 2; ++u)
        *(uint4*)&As[sra][sha + u * 8] = *(const uint4*)&s[(size_t)(m0 + sra) * CS + kt + sha + u * 8];
#pragma unroll
      for (int u = 0; u < 4; ++u)
        *(uint4*)&Bs[srb][shb + u * 8] = *(const uint4*)&B[(size_t)(nl0 + srb) * CS + kt + shb + u * 8];
      __syncthreads();
#pragma unroll
      for (int kk = 0; kk < 64; kk += 32) {
        bf16x8 af[2], bfr[4];
#pragma unroll
        for (int i = 0; i < 2; ++i) af[i] = *(const bf16x8*)&As[wm * 32 + i * 16 + c][kk + g * 8];
#pragma unroll
        for (int j = 0; j < 4; ++j) bfr[j] = *(const bf16x8*)&Bs[wn * 64 + j * 16 + c][kk + g * 8];
#pragma unroll
        for (int i = 0; i < 2; ++i)
#pragma unroll
          for (int j = 0; j < 4; ++j)
            acc[i][j] = __builtin_amdgcn_mfma_f32_16x16x32_bf16(af[i], bfr[j], acc[i][j], 0, 0, 0);
      }
    }
#pragma unroll
    for (int i = 0; i < 2; ++i) {
#pragma unroll
      for (int j = 0; j < 4; ++j) {
        const int mb = m0 + wm * 32 + i * 16 + g * 4;
        const int nn = nl0 + wn * 64 + j * 16 + c;
        const f32x4 a = acc[i][j];
        if (wid == 0) {
#pragma unroll
          for (int r = 0; r < 4; ++r) qb[(size_t)(mb + r) * CS + nn] = f2bf(a[r] * 0.125f);
        } else if (wid == 1) {
#pragma unroll
          for (int r = 0; r < 4; ++r) kb[(size_t)(mb + r) * CS + nn] = f2bf(a[r]);
        } else if (wid == 2) {
          ushort4 pk;
          pk.x = f2bf(a[0]); pk.y = f2bf(a[1]); pk.z = f2bf(a[2]); pk.w = f2bf(a[3]);
          *(ushort4*)&vt[(size_t)nn * LQ + mb] = pk;
        } else {
          const float bb = bg[nn];
#pragma unroll
          for (int r = 0; r < 4; ++r) gpre[(size_t)(mb + r) * CS + nn] = a[r] + bb;
        }
      }
    }
  }
}

// ============ kernel 3: MFMA flash attention, j-split x2, double-buffered ============
__global__ __launch_bounds__(256) void attn_k(
    const unsigned short* __restrict__ q, const unsigned short* __restrict__ k,
    const unsigned short* __restrict__ vt, const unsigned short* __restrict__ biasF,
    float* __restrict__ Opart, float* __restrict__ ml) {
  __shared__ __align__(16) unsigned short Qs[64][88];
  __shared__ __align__(16) unsigned short Ks[2][64][88];
  __shared__ __align__(16) unsigned short Vts[2][64][88];
  __shared__ __align__(16) unsigned short Ps[4][16][88];
  const int bx = blockIdx.x, h = blockIdx.y, z = blockIdx.z;
  const int i0 = bx * 64;
  const int jb = z * 512;
  const int t = threadIdx.x;
  const int w = t >> 6, lane = t & 63, g = lane >> 4, c = lane & 15;
  const int sr = t >> 2, sc = (t & 3) * 16;

#pragma unroll
  for (int u = 0; u < 2; ++u) {
    *(uint4*)&Qs[sr][sc + u * 8]     = *(const uint4*)&q[(size_t)(i0 + sr) * CS + h * HD + sc + u * 8];
    *(uint4*)&Ks[0][sr][sc + u * 8]  = *(const uint4*)&k[(size_t)(jb + sr) * CS + h * HD + sc + u * 8];
    *(uint4*)&Vts[0][sr][sc + u * 8] = *(const uint4*)&vt[(size_t)(h * HD + sr) * LQ + jb + sc + u * 8];
  }
  const size_t bbase = ((((size_t)h * 64 + (bx * 4 + w)) * 16 + (size_t)z * 8) * 4) * 256 + lane * 4;
  ushort4 bcur[4];
#pragma unroll
  for (int nb = 0; nb < 4; ++nb) bcur[nb] = *(const ushort4*)&biasF[bbase + nb * 256];
  __syncthreads();

  const bf16x8 aq0 = *(const bf16x8*)&Qs[w * 16 + c][g * 8];
  const bf16x8 aq1 = *(const bf16x8*)&Qs[w * 16 + c][32 + g * 8];

  f32x4 acc_o[4];
#pragma unroll
  for (int nb = 0; nb < 4; ++nb) acc_o[nb] = (f32x4){0.f, 0.f, 0.f, 0.f};
  float m_run[4] = {-1e30f, -1e30f, -1e30f, -1e30f};
  float l_run[4] = {0.f, 0.f, 0.f, 0.f};

  for (int jt = 0; jt < 8; ++jt) {
    const int cur = jt & 1;
    uint4 kr0, kr1, vr0, vr1;
    ushort4 bnx[4];
    if (jt < 7) {
      const int jn = jb + (jt + 1) * 64;
      kr0 = *(const uint4*)&k[(size_t)(jn + sr) * CS + h * HD + sc];
      kr1 = *(const uint4*)&k[(size_t)(jn + sr) * CS + h * HD + sc + 8];
      vr0 = *(const uint4*)&vt[(size_t)(h * HD + sr) * LQ + jn + sc];
      vr1 = *(const uint4*)&vt[(size_t)(h * HD + sr) * LQ + jn + sc + 8];
#pragma unroll
      for (int nb = 0; nb < 4; ++nb)
        bnx[nb] = *(const ushort4*)&biasF[bbase + (size_t)(jt + 1) * 1024 + nb * 256];
    }

    f32x4 sa[4];
#pragma unroll
    for (int nb = 0; nb < 4; ++nb) {
      f32x4 ci;
      ci[0] = bf2f(bcur[nb].x); ci[1] = bf2f(bcur[nb].y);
      ci[2] = bf2f(bcur[nb].z); ci[3] = bf2f(bcur[nb].w);
      const bf16x8 b0 = *(const bf16x8*)&Ks[cur][nb * 16 + c][g * 8];
      const bf16x8 b1 = *(const bf16x8*)&Ks[cur][nb * 16 + c][32 + g * 8];
      ci = __builtin_amdgcn_mfma_f32_16x16x32_bf16(aq0, b0, ci, 0, 0, 0);
      ci = __builtin_amdgcn_mfma_f32_16x16x32_bf16(aq1, b1, ci, 0, 0, 0);
      sa[nb] = ci;
    }

    float mt[4];
#pragma unroll
    for (int r = 0; r < 4; ++r) {
      float v = fmaxf(fmaxf(sa[0][r], sa[1][r]), fmaxf(sa[2][r], sa[3][r]));
      v = fmaxf(v, __shfl_xor(v, 1));
      v = fmaxf(v, __shfl_xor(v, 2));
      v = fmaxf(v, __shfl_xor(v, 4));
      v = fmaxf(v, __shfl_xor(v, 8));
      mt[r] = v;
    }
    float scale[4], ps[4];
#pragma unroll
    for (int r = 0; r < 4; ++r) {
      const float mn = fmaxf(m_run[r], mt[r]);
      scale[r] = __expf(m_run[r] - mn);
      m_run[r] = mn;
      ps[r] = 0.f;
    }
#pragma unroll
    for (int nb = 0; nb < 4; ++nb) {
#pragma unroll
      for (int r = 0; r < 4; ++r) {
        const float p = __expf(sa[nb][r] - m_run[r]);
        ps[r] += p;
        Ps[w][g * 4 + r][nb * 16 + c] = f2bf(p);
      }
    }
#pragma unroll
    for (int r = 0; r < 4; ++r) {
      float v = ps[r];
      v += __shfl_xor(v, 1);
      v += __shfl_xor(v, 2);
      v += __shfl_xor(v, 4);
      v += __shfl_xor(v, 8);
      l_run[r] = l_run[r] * scale[r] + v;
#pragma unroll
      for (int nb = 0; nb < 4; ++nb) acc_o[nb][r] *= scale[r];
    }

#pragma unroll
    for (int kb = 0; kb < 2; ++kb) {
      const bf16x8 pa = *(const bf16x8*)&Ps[w][c][kb * 32 + g * 8];
#pragma unroll
      for (int nb = 0; nb < 4; ++nb) {
        const bf16x8 bv = *(const bf16x8*)&Vts[cur][nb * 16 + c][kb * 32 + g * 8];
        acc_o[nb] = __builtin_amdgcn_mfma_f32_16x16x32_bf16(pa, bv, acc_o[nb], 0, 0, 0);
      }
    }

    if (jt < 7) {
      *(uint4*)&Ks[cur ^ 1][sr][sc]      = kr0;
      *(uint4*)&Ks[cur ^ 1][sr][sc + 8]  = kr1;
      *(uint4*)&Vts[cur ^ 1][sr][sc]     = vr0;
      *(uint4*)&Vts[cur ^ 1][sr][sc + 8] = vr1;
      __syncthreads();
#pragma unroll
      for (int nb = 0; nb < 4; ++nb) bcur[nb] = bnx[nb];
    }
  }

  const size_t rowb = (size_t)(z * NH + h) * LQ + i0 + w * 16 + g * 4;
#pragma unroll
  for (int nb = 0; nb < 4; ++nb)
#pragma unroll
    for (int r = 0; r < 4; ++r)
      Opart[(rowb + r) * HD + nb * 16 + c] = acc_o[nb][r];
  if (c == 0) {
#pragma unroll
    for (int r = 0; r < 4; ++r) {
      ml[(rowb + r) * 2]     = m_run[r];
      ml[(rowb + r) * 2 + 1] = l_run[r];
    }
  }
}

// ============ kernel 4: combine the two j-halves ============
__global__ __launch_bounds__(256) void combine_k(
    const float* __restrict__ Opart, const float* __restrict__ ml,
    unsigned short* __restrict__ attno) {
  const int t = threadIdx.x;
  const int row = blockIdx.x * 4 + (t >> 6);
  const int d = t & 63;
  const int h = row >> 10, i = row & 1023;
  const size_t r0 = (size_t)h * LQ + i;
  const size_t r1 = (size_t)(NH + h) * LQ + i;
  const float m0 = ml[r0 * 2], l0 = ml[r0 * 2 + 1];
  const float m1 = ml[r1 * 2], l1 = ml[r1 * 2 + 1];
  const float M = fmaxf(m0, m1);
  const float a0 = __expf(m0 - M), a1 = __expf(m1 - M);
  const float L = a0 * l0 + a1 * l1;
  const float o = (a0 * Opart[r0 * HD + d] + a1 * Opart[r1 * HD + d]) / L;
  attno[(size_t)i * CS + h * HD + d] = f2bf(o);
}

// ============ kernel 5: final GEMM (64x128 tiles) + gated residual ============
__global__ __launch_bounds__(256) void gemm_final_k(
    const unsigned short* __restrict__ A, const unsigned short* __restrict__ wt,
    const float* __restrict__ bout, const float* __restrict__ single,
    const float* __restrict__ gpre, float* __restrict__ out) {
  __shared__ __align__(16) unsigned short As[64][88];
  __shared__ __align__(16) unsigned short Bs[128][88];
  const int t = threadIdx.x;
  const int wave = t >> 6, lane = t & 63, g = lane >> 4, c = lane & 15;
  const int wm = wave >> 1, wn = wave & 1;
  const int m0 = blockIdx.y * 64;
  const int nl0 = blockIdx.x * 128;
  const unsigned short* B = wt + (size_t)4 * CS * CS;

  f32x4 acc[2][4];
#pragma unroll
  for (int i = 0; i < 2; ++i)
#pragma unroll
    for (int j = 0; j < 4; ++j) acc[i][j] = (f32x4){0.f, 0.f, 0.f, 0.f};

  const int sra = t >> 2, sha = (t & 3) * 16;
  const int srb = t >> 1, shb = (t & 1) * 32;
  for (int kt = 0; kt < CS; kt += 64) {
    __syncthreads();
#pragma unroll
    for (int u = 0; u < 2; ++u)
      *(uint4*)&As[sra][sha + u * 8] = *(const uint4*)&A[(size_t)(m0 + sra) * CS + kt + sha + u * 8];
#pragma unroll
    for (int u = 0; u < 4; ++u)
      *(uint4*)&Bs[srb][shb + u * 8] = *(const uint4*)&B[(size_t)(nl0 + srb) * CS + kt + shb + u * 8];
    __syncthreads();
#pragma unroll
    for (int kk = 0; kk < 64; kk += 32) {
      bf16x8 af[2], bfr[4];
#pragma unroll
      for (int i = 0; i < 2; ++i) af[i] = *(const bf16x8*)&As[wm * 32 + i * 16 + c][kk + g * 8];
#pragma unroll
      for (int j = 0; j < 4; ++j) bfr[j] = *(const bf16x8*)&Bs[wn * 64 + j * 16 + c][kk + g * 8];
#pragma unroll
      for (int i = 0; i < 2; ++i)
#pragma unroll
        for (int j = 0; j < 4; ++j)
          acc[i][j] = __builtin_amdgcn_mfma_f32_16x16x32_bf16(af[i], bfr[j], acc[i][j], 0, 0, 0);
    }
  }

#pragma unroll
  for (int i = 0; i < 2; ++i) {
#pragma unroll
    for (int j = 0; j < 4; ++j) {
      const int mb = m0 + wm * 32 + i * 16 + g * 4;
      const int nn = nl0 + wn * 64 + j * 16 + c;
      const float bb = bout[nn];
      const f32x4 a = acc[i][j];
#pragma unroll
      for (int r = 0; r < 4; ++r) {
        const size_t idx = (size_t)(mb + r) * CS + nn;
        const float gate = 1.f / (1.f + __expf(-gpre[idx]));
        out[idx] = single[idx] + gate * (a[r] + bb);
      }
    }
  }
}

extern "C" void kernel_launch(void* const* d_in, const int* in_sizes, int n_in,
                              void* d_out, int out_size, void* d_ws, size_t ws_size,
                              hipStream_t stream) {
  const float* single = (const float*)d_in[0];
  const float* pair   = (const float*)d_in[1];
  const float* ln_s_g = (const float*)d_in[2];
  const float* ln_s_b = (const float*)d_in[3];
  const float* ln_z_g = (const float*)d_in[4];
  const float* ln_z_b = (const float*)d_in[5];
  const float* Wq     = (const float*)d_in[6];
  const float* Wk     = (const float*)d_in[7];
  const float* Wv     = (const float*)d_in[8];
  const float* Wb     = (const float*)d_in[9];
  const float* Wout   = (const float*)d_in[10];
  const float* bout   = (const float*)d_in[11];
  const float* Wgate  = (const float*)d_in[12];
  const float* bgate  = (const float*)d_in[13];
  float* out = (float*)d_out;

  unsigned short* s_bf  = (unsigned short*)d_ws;
  unsigned short* wt    = s_bf  + (size_t)LQ * CS;
  unsigned short* q_bf  = wt    + (size_t)5 * CS * CS;
  unsigned short* k_bf  = q_bf  + (size_t)LQ * CS;
  unsigned short* vt_bf = k_bf  + (size_t)LQ * CS;
  unsigned short* attno = vt_bf + (size_t)CS * LQ;
  unsigned short* biasF = attno + (size_t)LQ * CS;
  float* gpre  = (float*)(biasF + (size_t)NH * LQ * LQ);
  float* Opart = gpre  + (size_t)LQ * CS;
  float* mlw   = Opart + (size_t)2 * NH * LQ * HD;

  hipLaunchKernelGGL(ln_wconv_k, dim3(LQ + 720), dim3(256), 0, stream,
                     single, ln_s_g, ln_s_b, s_bf, Wq, Wk, Wv, Wgate, Wout, wt);
  hipLaunchKernelGGL(qkvg_pair_k, dim3(2048 + 384), dim3(256), 0, stream,
                     s_bf, wt, bgate, q_bf, k_bf, vt_bf, gpre,
                     pair, ln_z_g, ln_z_b, Wb, biasF);
  hipLaunchKernelGGL(attn_k, dim3(16, NH, 2), dim3(256), 0, stream,
                     q_bf, k_bf, vt_bf, biasF, Opart, mlw);
  hipLaunchKernelGGL(combine_k, dim3(3072), dim3(256), 0, stream,
                     Opart, mlw, attno);
  hipLaunchKernelGGL(gemm_final_k, dim3(6, 16), dim3(256), 0, stream,
                     attno, wt, bout, single, gpre, out);
}